// Round 3
// baseline (197.128 us; speedup 1.0000x reference)
//
#include <hip/hip_runtime.h>
#include <hip/hip_bf16.h>
#include <math.h>

typedef __attribute__((ext_vector_type(8))) short short8;
typedef __attribute__((ext_vector_type(4))) float floatx4;
typedef unsigned short ushortT;

__device__ inline short f2bf(float v) {
    __hip_bfloat16 h = __float2bfloat16(v);
    union { __hip_bfloat16 h; short s; } u; u.h = h; return u.s;
}
// agent-scope (device) coherent stores/loads for cross-XCD partial handoff
__device__ inline void gstore(float* p, float v) {
    __hip_atomic_store(p, v, __ATOMIC_RELAXED, __HIP_MEMORY_SCOPE_AGENT);
}
__device__ inline float gload(const float* p) {
    return __hip_atomic_load(p, __ATOMIC_RELAXED, __HIP_MEMORY_SCOPE_AGENT);
}

// ---------------- workspace layout (bytes), all disjoint ----------------
#define OFF_C2    0
#define OFF_PAD4  8388608
#define OFF_FICH  12849152
#define OFF_PAD2  21237760
#define OFF_PAD3  29890560
#define OFF_WP2   32120832
#define OFF_WP3   32194560
#define OFF_WP4   32342016
#define OFF_ST    33947648   // [0..127] rstdF (written by conv4_bn last block)
#define OFF_CNT   33948160   // int ticket counter (modularity)
#define OFF_CNT2  33948224   // int ticket counter (conv4_bn)
#define OFF_P64   33951744   // 256 x 16 floats mod64 partials
#define OFF_P128  33968128   // 1024 x 16 floats mod128 partials
#define OFF_PBN   34033664   // 512 x 64 floats conv4 bn partials (128KB)
#define OFF_PIMG  34295808   // 192 x 2 floats image bn partials

// ---------------- prologue: halos + weight prepack + image bnsum + conv1 ----
__global__ __launch_bounds__(256) void prologue(
    char* ws, const float* __restrict__ images,
    const float* __restrict__ w1, const float* __restrict__ b1,
    const float* __restrict__ w2, const float* __restrict__ w3,
    const float* __restrict__ w4)
{
    __shared__ float plds[3 * 720];
    __shared__ float rs[256], rs2[256];

    int b = blockIdx.x;
    int tid = threadIdx.x;

    if (b == 0 && tid == 0) {
        *(int*)(ws + OFF_CNT) = 0;
        *(int*)(ws + OFF_CNT2) = 0;
    }

    if (b >= 1362) {
        // ---- conv1 body ----
        int bid = b - 1362;                   // 4n x 8ocg x 8ty x 8tx
        int txt = bid & 7; bid >>= 3;
        int tyt = bid & 7; bid >>= 3;
        int ocg = bid & 7; bid >>= 3;
        int n = bid;
        int x0 = txt * 16, y0 = tyt * 16;
        int tx = tid & 15, ty = tid >> 4;
        short* outp = (short*)(ws + OFF_PAD2);

        for (int i = tid; i < 972; i += 256) {
            int cc = i / 324; int rem = i - cc * 324;
            int r = rem / 18, c = rem - r * 18;
            int y = y0 - 1 + r, x = x0 - 1 + c;
            float v = 0.f;
            if ((unsigned)y < 128u && (unsigned)x < 128u)
                v = images[((size_t)(n * 3 + cc) * 128 + y) * 128 + x];
            plds[cc * 720 + r * 40 + c] = v;
        }
        __syncthreads();

        float acc[8];
#pragma unroll
        for (int oc = 0; oc < 8; ++oc) acc[oc] = 0.f;
        const float* w_g = w1 + (size_t)(ocg * 8) * 27;
#pragma unroll
        for (int cc = 0; cc < 3; ++cc) {
            const float* base = &plds[cc * 720 + ty * 40 + tx];
            float i00 = base[0],  i01 = base[1],  i02 = base[2];
            float i10 = base[40], i11 = base[41], i12 = base[42];
            float i20 = base[80], i21 = base[81], i22 = base[82];
            const float* wp = w_g + cc * 9;
#pragma unroll
            for (int oc = 0; oc < 8; ++oc) {
                const float* wq = wp + oc * 27;
                float a = acc[oc];
                a = fmaf(wq[0], i00, a); a = fmaf(wq[1], i01, a); a = fmaf(wq[2], i02, a);
                a = fmaf(wq[3], i10, a); a = fmaf(wq[4], i11, a); a = fmaf(wq[5], i12, a);
                a = fmaf(wq[6], i20, a); a = fmaf(wq[7], i21, a); a = fmaf(wq[8], i22, a);
                acc[oc] = a;
            }
        }
        int oy = y0 + ty, ox = x0 + tx;
        short* o = outp + ((size_t)(n * 130 + oy + 1) * 130 + ox + 1) * 64 + ocg * 8;
#pragma unroll
        for (int oc = 0; oc < 8; ++oc) {
            float v = fmaxf(acc[oc] + b1[ocg * 8 + oc], 0.f);
            o[oc] = f2bf(v);
        }
        return;
    }

    if (b < 162) {
        int t = b * 256 + tid;
        short* base; int Hp, Wp, C; int idx;
        if (t < 16512)      { base = (short*)(ws + OFF_PAD2); Hp = 130; Wp = 130; C = 64;  idx = t; }
        else if (t < 24832) { base = (short*)(ws + OFF_PAD3); Hp = 66;  Wp = 66;  C = 64;  idx = t - 16512; }
        else if (t < 41472) { base = (short*)(ws + OFF_PAD4); Hp = 66;  Wp = 66;  C = 128; idx = t - 24832; }
        else return;
        int c8 = idx % (C / 8); int rest = idx / (C / 8);
        int haloPx = 2 * Wp + 2 * (Hp - 2);
        int p = rest % haloPx; int n = rest / haloPx;
        int y, x;
        if (p < Wp)          { y = 0;      x = p; }
        else if (p < 2 * Wp) { y = Hp - 1; x = p - Wp; }
        else { int j = p - 2 * Wp; y = 1 + (j >> 1); x = (j & 1) ? (Wp - 1) : 0; }
        short8 z = {0, 0, 0, 0, 0, 0, 0, 0};
        *(short8*)&base[((size_t)((n * Hp + y) * Wp) + x) * C + c8 * 8] = z;
        return;
    }
    if (b < 1170) {
        int e = (b - 162) * 256 + tid;
        const float* w; short* wp; int CIN, NTALL;
        if (e < 36864)       { w = w2; wp = (short*)(ws + OFF_WP2); CIN = 64;  NTALL = 4; }
        else if (e < 110592) { e -= 36864;  w = w3; wp = (short*)(ws + OFF_WP3); CIN = 64;  NTALL = 8; }
        else if (e < 258048) { e -= 110592; w = w4; wp = (short*)(ws + OFF_WP4); CIN = 128; NTALL = 8; }
        else return;
        int j = e & 7; int L = (e >> 3) & 63; int rest = e >> 9;
        int nt = rest % NTALL; int rest2 = rest / NTALL;
        int KT = CIN / 32;
        int kt = rest2 % KT; int t = rest2 / KT;
        int oc = nt * 16 + (L & 15);
        int ci = kt * 32 + (L >> 4) * 8 + j;
        wp[e] = f2bf(w[((size_t)oc * CIN + ci) * 9 + t]);
        return;
    }
    {
        float* part = (float*)(ws + OFF_PIMG);
        int bb = b - 1170;           // c(3) x chunk(64)
        int c = bb >> 6, chunk = bb & 63;
        int base = chunk * 1024 + tid;
        float s = 0.f, s2 = 0.f;
#pragma unroll
        for (int k = 0; k < 4; ++k) {
            int i = base + k * 256;
            int n = i >> 14, hw = i & 16383;
            float v = images[(((size_t)(n * 3 + c)) << 14) + hw];
            s += v; s2 = fmaf(v, v, s2);
        }
        rs[tid] = s; rs2[tid] = s2;
        __syncthreads();
        for (int k = 128; k > 0; k >>= 1) {
            if (tid < k) { rs[tid] += rs[tid + k]; rs2[tid] += rs2[tid + k]; }
            __syncthreads();
        }
        if (tid == 0) { part[bb * 2] = rs[0]; part[bb * 2 + 1] = rs2[0]; }
    }
}

// ---------------- conv2 (64->64, 128x128) + fused 2x2 maxpool ---------------
// 4 conv rows (2 pooled rows) per block, oc split 2-way: 512 blocks.
__global__ __launch_bounds__(256) void conv2_pool(
    const short* __restrict__ inp,  // PAD2 (4,130,130,64) bf16
    const short* __restrict__ wp,   // WP2
    const float* __restrict__ bias,
    short* __restrict__ outp)       // PAD3 (4,66,66,64) bf16
{
    constexpr int CIN = 64;
    constexpr int Hp = 130, Wp = 130;

    int bid = blockIdx.x;           // 512 = n4 x yq32 x xt2 x o2
    int o2 = bid & 1; bid >>= 1;
    int xt = bid & 1; bid >>= 1;
    int yq = bid & 31; bid >>= 5;
    int n = bid;
    int y0 = yq * 4;                // conv row base; reads PAD2 rows y0..y0+5
    int x0 = xt * 64;

    int tid = threadIdx.x;
    int wv = tid >> 6, lane = tid & 63;
    int lm = lane & 15, q = lane >> 4;
    int px0 = x0 + 16 * wv;
    int ntb = o2 * 2;               // 2 nt-tiles = 32 oc

    floatx4 acc[4][2];
#pragma unroll
    for (int d = 0; d < 4; ++d)
#pragma unroll
        for (int t = 0; t < 2; ++t) acc[d][t] = (floatx4){0.f, 0.f, 0.f, 0.f};

    const short* a_m = inp + lm * CIN + q * 8;
    const short* wbase = wp + ((size_t)ntb * 64 + lane) * 8;

    for (int kt = 0; kt < 2; ++kt) {
        int kofs = kt * 32;
#pragma unroll
        for (int s = 0; s < 3; ++s) {
            const short* acol = a_m + ((size_t)((n * Hp + y0) * Wp) + px0 + s) * CIN + kofs;
            short8 av[6];
#pragma unroll
            for (int j = 0; j < 6; ++j)
                av[j] = *(const short8*)(acol + (size_t)j * Wp * CIN);
#pragma unroll
            for (int r = 0; r < 3; ++r) {
                const short* bp = wbase + (size_t)(((r * 3 + s) * 2 + kt) * 4) * 512;
                short8 b0 = *(const short8*)bp;
                short8 b1 = *(const short8*)(bp + 512);
#pragma unroll
                for (int d = 0; d < 4; ++d) {
                    acc[d][0] = __builtin_amdgcn_mfma_f32_16x16x32_bf16(av[r + d], b0, acc[d][0], 0, 0, 0);
                    acc[d][1] = __builtin_amdgcn_mfma_f32_16x16x32_bf16(av[r + d], b1, acc[d][1], 0, 0, 0);
                }
            }
        }
    }

    // epilogue: relu + 2x2 pool in-register -> PAD3 interior
    int ox = (px0 + q * 4) >> 1;
#pragma unroll
    for (int t2 = 0; t2 < 2; ++t2) {
        int oc = (ntb + t2) * 16 + lm;
        float bs = bias[oc];
#pragma unroll
        for (int p = 0; p < 2; ++p) {
            float v00 = fmaxf(acc[2 * p][t2][0] + bs, 0.f);
            float v01 = fmaxf(acc[2 * p][t2][1] + bs, 0.f);
            float v02 = fmaxf(acc[2 * p][t2][2] + bs, 0.f);
            float v03 = fmaxf(acc[2 * p][t2][3] + bs, 0.f);
            float v10 = fmaxf(acc[2 * p + 1][t2][0] + bs, 0.f);
            float v11 = fmaxf(acc[2 * p + 1][t2][1] + bs, 0.f);
            float v12 = fmaxf(acc[2 * p + 1][t2][2] + bs, 0.f);
            float v13 = fmaxf(acc[2 * p + 1][t2][3] + bs, 0.f);
            float m0 = fmaxf(fmaxf(v00, v01), fmaxf(v10, v11));
            float m1 = fmaxf(fmaxf(v02, v03), fmaxf(v12, v13));
            int oy = yq * 2 + p;
            short* o = outp + ((size_t)(n * 66 + oy + 1) * 66 + ox + 1) * 64 + oc;
            o[0]  = f2bf(m0);
            o[64] = f2bf(m1);
        }
    }
}

// ---------------- conv3 (64->128, 64x64): 2 rows/block, oc split 4 ----------
__global__ __launch_bounds__(256) void conv3_2row(
    const short* __restrict__ inp,  // PAD3 (4,66,66,64)
    const short* __restrict__ wp,   // WP3
    const float* __restrict__ bias,
    short* __restrict__ outp)       // PAD4 (4,66,66,128) interior
{
    constexpr int CIN = 64, COUT = 128, Hp = 66, Wp = 66, KT = 2, NTALL = 8;

    int bid = blockIdx.x;           // 512 = n4 x yq32 x bn4
    int bn = bid & 3; bid >>= 2;
    int yq = bid & 31; bid >>= 5;
    int n = bid;
    int y0 = yq * 2;

    int tid = threadIdx.x;
    int wv = tid >> 6, lane = tid & 63;
    int lm = lane & 15, q = lane >> 4;
    int px0 = 16 * wv;
    int ntb = bn * 2;

    floatx4 acc[2][2];
#pragma unroll
    for (int d = 0; d < 2; ++d)
#pragma unroll
        for (int t = 0; t < 2; ++t) acc[d][t] = (floatx4){0.f, 0.f, 0.f, 0.f};

    const short* a_m = inp + lm * CIN + q * 8;
    const short* wbase = wp + ((size_t)ntb * 64 + lane) * 8;

    for (int kt = 0; kt < KT; ++kt) {
        int kofs = kt * 32;
#pragma unroll
        for (int s = 0; s < 3; ++s) {
            const short* acol = a_m + ((size_t)((n * Hp + y0) * Wp) + px0 + s) * CIN + kofs;
            short8 av[4];
#pragma unroll
            for (int j = 0; j < 4; ++j)
                av[j] = *(const short8*)(acol + (size_t)j * Wp * CIN);
#pragma unroll
            for (int r = 0; r < 3; ++r) {
                const short* bp = wbase + (size_t)(((r * 3 + s) * KT + kt) * NTALL) * 512;
                short8 b0 = *(const short8*)bp;
                short8 b1 = *(const short8*)(bp + 512);
#pragma unroll
                for (int d = 0; d < 2; ++d) {
                    acc[d][0] = __builtin_amdgcn_mfma_f32_16x16x32_bf16(av[r + d], b0, acc[d][0], 0, 0, 0);
                    acc[d][1] = __builtin_amdgcn_mfma_f32_16x16x32_bf16(av[r + d], b1, acc[d][1], 0, 0, 0);
                }
            }
        }
    }

#pragma unroll
    for (int t2 = 0; t2 < 2; ++t2) {
        int oc = (ntb + t2) * 16 + lm;
        float bs = bias[oc];
#pragma unroll
        for (int d = 0; d < 2; ++d) {
#pragma unroll
            for (int i = 0; i < 4; ++i) {
                int px = px0 + q * 4 + i;
                float v = fmaxf(acc[d][t2][i] + bs, 0.f);
                outp[((size_t)(n * Hp + y0 + d + 1) * Wp + px + 1) * COUT + oc] = f2bf(v);
            }
        }
    }
}

// ---------------- conv4 (128->128, 64x64): 2 rows/block + BN partials -------
// Last block (ticket) reduces PBN -> ST[128] rstd, saving a dispatch without
// redundant per-block work.
__global__ __launch_bounds__(256) void conv4_bn(
    const short* __restrict__ inp,  // PAD4 (4,66,66,128)
    const short* __restrict__ wp,   // WP4
    const float* __restrict__ bias,
    float* __restrict__ out,        // FICH (4,64,64,128) f32
    float* __restrict__ part,       // [512][64]: (sum,sumsq) x 32ch per block
    float* __restrict__ st,         // [128] rstd output
    int* __restrict__ cnt2)
{
    constexpr int CIN = 128, Hp = 66, Wp = 66, KT = 4, NTALL = 8;

    int bid = blockIdx.x;           // 512 = n4 x yq32 x bn4
    int bn = bid & 3; bid >>= 2;
    int yq = bid & 31; bid >>= 5;
    int n = bid;
    int y0 = yq * 2;

    int tid = threadIdx.x;
    int wv = tid >> 6, lane = tid & 63;
    int lm = lane & 15, q = lane >> 4;
    int px0 = 16 * wv;
    int ntb = bn * 2;

    floatx4 acc[2][2];
#pragma unroll
    for (int d = 0; d < 2; ++d)
#pragma unroll
        for (int t = 0; t < 2; ++t) acc[d][t] = (floatx4){0.f, 0.f, 0.f, 0.f};

    const short* a_m = inp + lm * CIN + q * 8;
    const short* wbase = wp + ((size_t)ntb * 64 + lane) * 8;

    for (int kt = 0; kt < KT; ++kt) {
        int kofs = kt * 32;
#pragma unroll
        for (int s = 0; s < 3; ++s) {
            const short* acol = a_m + ((size_t)((n * Hp + y0) * Wp) + px0 + s) * CIN + kofs;
            short8 av[4];
#pragma unroll
            for (int j = 0; j < 4; ++j)
                av[j] = *(const short8*)(acol + (size_t)j * Wp * CIN);
#pragma unroll
            for (int r = 0; r < 3; ++r) {
                const short* bp = wbase + (size_t)(((r * 3 + s) * KT + kt) * NTALL) * 512;
                short8 b0 = *(const short8*)bp;
                short8 b1 = *(const short8*)(bp + 512);
#pragma unroll
                for (int d = 0; d < 2; ++d) {
                    acc[d][0] = __builtin_amdgcn_mfma_f32_16x16x32_bf16(av[r + d], b0, acc[d][0], 0, 0, 0);
                    acc[d][1] = __builtin_amdgcn_mfma_f32_16x16x32_bf16(av[r + d], b1, acc[d][1], 0, 0, 0);
                }
            }
        }
    }

    __shared__ float ps[4][2][16], ps2[4][2][16];
    __shared__ float red[256], red2[256];
    __shared__ int lastf;
#pragma unroll
    for (int t2 = 0; t2 < 2; ++t2) {
        int oc = (ntb + t2) * 16 + lm;
        float bs = bias[oc];
        float sv = 0.f, sv2 = 0.f;
#pragma unroll
        for (int d = 0; d < 2; ++d) {
#pragma unroll
            for (int i = 0; i < 4; ++i) {
                int px = px0 + q * 4 + i;
                float v = fmaxf(acc[d][t2][i] + bs, 0.f);
                out[((size_t)(n * 64 + y0 + d) * 64 + px) * 128 + oc] = v;
                sv += v; sv2 = fmaf(v, v, sv2);
            }
        }
        sv  += __shfl_xor(sv, 16, 64);  sv  += __shfl_xor(sv, 32, 64);
        sv2 += __shfl_xor(sv2, 16, 64); sv2 += __shfl_xor(sv2, 32, 64);
        if (q == 0) { ps[wv][t2][lm] = sv; ps2[wv][t2][lm] = sv2; }
    }
    __syncthreads();
    if (tid < 32) {
        int t_ = tid >> 4, lm_ = tid & 15;
        float a  = ps[0][t_][lm_] + ps[1][t_][lm_] + ps[2][t_][lm_] + ps[3][t_][lm_];
        float a2 = ps2[0][t_][lm_] + ps2[1][t_][lm_] + ps2[2][t_][lm_] + ps2[3][t_][lm_];
        gstore(&part[(size_t)blockIdx.x * 64 + tid * 2],     a);
        gstore(&part[(size_t)blockIdx.x * 64 + tid * 2 + 1], a2);
    }

    // ---- ticket: last conv4 block reduces PBN -> ST (once) ----
    __syncthreads();
    if (tid == 0) {
        int old = __hip_atomic_fetch_add(cnt2, 1, __ATOMIC_ACQ_REL, __HIP_MEMORY_SCOPE_AGENT);
        lastf = (old == 511);
    }
    __syncthreads();
    if (!lastf) return;

    {
        int c = tid & 127, h = tid >> 7;
        int bn2 = c >> 5, lc = c & 31;
        float s = 0.f, s2 = 0.f;
        const float* pb = part + lc * 2;
#pragma unroll 8
        for (int i = 0; i < 64; ++i) {
            int b = (h * 64 + i) * 4 + bn2;
            s  += gload(pb + (size_t)b * 64);
            s2 += gload(pb + (size_t)b * 64 + 1);
        }
        red[tid] = s; red2[tid] = s2;
        __syncthreads();
        if (tid < 128) {
            float ss = red[tid] + red[tid + 128];
            float qq = red2[tid] + red2[tid + 128];
            float mean = ss * (1.f / 16384.f);
            float var = qq * (1.f / 16384.f) - mean * mean;
            gstore(&st[tid], 1.f / sqrtf(var + 1e-5f));
        }
    }
}

// ---------------- modularity bodies (shared-LDS merged dispatch) ------------
__device__ __forceinline__ void mod64_body(
    int obid,
    const float* __restrict__ xt, const float* __restrict__ seg,
    const float* __restrict__ st, float* __restrict__ part,
    float* fl, float (*sl)[12][14])
{
    int tid = threadIdx.x;
    int w = tid >> 6, lane = tid & 63;
    int tx = lane & 7, ty = lane >> 3;
    int bid = obid;
    int bx = bid & 7; bid >>= 3;
    int by = bid & 7; bid >>= 3;
    int n = bid;
    int x0 = bx * 8, y0 = by * 8;

    for (int i = tid; i < 8 * 144; i += 256) {
        int k = i / 144;
        int rem = i - k * 144;
        int r = rem / 12, c = rem - r * 12;
        int y = y0 - 2 + r, x = x0 - 2 + c;
        float v = 0.f;
        if ((unsigned)y < 64u && (unsigned)x < 64u) {
            const float* p = seg + ((size_t)(n * 8 + k) * 128 + 2 * y) * 128 + 2 * x;
            float2 a = *(const float2*)p;
            float2 b = *(const float2*)(p + 128);
            v = 0.25f * ((a.x + a.y) + (b.x + b.y));
        }
        sl[k][r][c] = v;
    }

    float* slab = fl + w * 2880;

    float d2p[25];
#pragma unroll
    for (int di = 0; di < 5; ++di)
#pragma unroll
        for (int dj = 0; dj < 5; ++dj) {
            int y2 = y0 + ty + di - 2, x2 = x0 + tx + dj - 2;
            float bias = ((unsigned)y2 < 64u && (unsigned)x2 < 64u) ? 0.f : 1e30f;
            d2p[di * 5 + dj] = (w == 0) ? bias : 0.f;
        }

    for (int r8 = 0; r8 < 2; ++r8) {
        int ch0 = w * 32 + r8 * 16;
        for (int i = lane; i < 576; i += 64) {
            int pix = i >> 2, q = i & 3;
            int r = pix / 12, c = pix - r * 12;
            int y = y0 - 2 + r, x = x0 - 2 + c;
            float4 v = make_float4(0.f, 0.f, 0.f, 0.f);
            if ((unsigned)y < 64u && (unsigned)x < 64u) {
                v = *(const float4*)&xt[((size_t)((n * 64 + y) * 64 + x)) * 128 + ch0 + q * 4];
                float4 sv = *(const float4*)&st[ch0 + q * 4];
                v.x *= sv.x; v.y *= sv.y; v.z *= sv.z; v.w *= sv.w;
            }
            *(float4*)&slab[(r * 12 + c) * 20 + q * 4] = v;
        }

        const float* ctr = &slab[((ty + 2) * 12 + tx + 2) * 20];
        float4 c0 = *(const float4*)(ctr + 0);
        float4 c1 = *(const float4*)(ctr + 4);
        float4 c2 = *(const float4*)(ctr + 8);
        float4 c3 = *(const float4*)(ctr + 12);
#pragma unroll
        for (int di = 0; di < 5; ++di)
#pragma unroll
            for (int dj = 0; dj < 5; ++dj) {
                const float* np = &slab[((ty + di) * 12 + tx + dj) * 20];
                float4 v0 = *(const float4*)(np + 0);
                float4 v1 = *(const float4*)(np + 4);
                float4 v2 = *(const float4*)(np + 8);
                float4 v3 = *(const float4*)(np + 12);
                float d = d2p[di * 5 + dj];
                float e;
                e = c0.x - v0.x; d = fmaf(e, e, d);
                e = c0.y - v0.y; d = fmaf(e, e, d);
                e = c0.z - v0.z; d = fmaf(e, e, d);
                e = c0.w - v0.w; d = fmaf(e, e, d);
                e = c1.x - v1.x; d = fmaf(e, e, d);
                e = c1.y - v1.y; d = fmaf(e, e, d);
                e = c1.z - v1.z; d = fmaf(e, e, d);
                e = c1.w - v1.w; d = fmaf(e, e, d);
                e = c2.x - v2.x; d = fmaf(e, e, d);
                e = c2.y - v2.y; d = fmaf(e, e, d);
                e = c2.z - v2.z; d = fmaf(e, e, d);
                e = c2.w - v2.w; d = fmaf(e, e, d);
                e = c3.x - v3.x; d = fmaf(e, e, d);
                e = c3.y - v3.y; d = fmaf(e, e, d);
                e = c3.z - v3.z; d = fmaf(e, e, d);
                e = c3.w - v3.w; d = fmaf(e, e, d);
                d2p[di * 5 + dj] = d;
            }
    }

#pragma unroll
    for (int j = 0; j < 25; ++j) slab[lane * 25 + j] = d2p[j];
    __syncthreads();

    const float minus_inv2s2 = -1.0f / (2.0f * 0.02f * 0.02f); // -1250
    for (int i = tid; i < 1600; i += 256) {
        float d = fl[i] + fl[2880 + i] + fl[5760 + i] + fl[8640 + i];
        fl[i] = expf(d * minus_inv2s2);
    }
    __syncthreads();

    float wgt[25];
    float w1 = 0.f;
#pragma unroll
    for (int j = 0; j < 25; ++j) { wgt[j] = fl[lane * 25 + j]; w1 += wgt[j]; }
#pragma unroll
    for (int kk = 0; kk < 2; ++kk) {
        int k = w * 2 + kk;
        float s = 0.f;
#pragma unroll
        for (int di = 0; di < 5; ++di)
#pragma unroll
            for (int dj = 0; dj < 5; ++dj)
                s = fmaf(wgt[di * 5 + dj], sl[k][ty + di][tx + dj], s);
        float sc = sl[k][ty + 2][tx + 2];
        float numk = s * sc;
        float denk = w1 * sc;
#pragma unroll
        for (int sh = 32; sh > 0; sh >>= 1) {
            numk += __shfl_xor(numk, sh, 64);
            denk += __shfl_xor(denk, sh, 64);
        }
        if (lane == 0) {
            gstore(&part[(size_t)obid * 16 + k * 2], numk);
            gstore(&part[(size_t)obid * 16 + k * 2 + 1], denk);
        }
    }
}

__device__ __forceinline__ void mod128_body(
    int obid,
    const float* __restrict__ img, const float* __restrict__ pimg,
    const float* __restrict__ seg, float* __restrict__ part,
    float (*il)[12][4], float (*sl)[12][14], float* stm)
{
    int t = threadIdx.x;            // 256
    int w = t >> 6, lane = t & 63;
    int tx = lane & 7, ty = lane >> 3;

    if (t < 64) {
#pragma unroll
        for (int ch = 0; ch < 3; ++ch) {
            float s  = pimg[(ch * 64 + t) * 2];
            float s2 = pimg[(ch * 64 + t) * 2 + 1];
#pragma unroll
            for (int sh = 32; sh > 0; sh >>= 1) {
                s += __shfl_xor(s, sh, 64);
                s2 += __shfl_xor(s2, sh, 64);
            }
            if (t == 0) {
                float mean = s * (1.f / 65536.f);
                float var = s2 * (1.f / 65536.f) - mean * mean;
                stm[ch] = mean;
                stm[3 + ch] = 1.f / sqrtf(var + 1e-5f);
            }
        }
    }

    int bid = obid;                    // n(4) x by(16) x bx(16)
    int bx = bid & 15; bid >>= 4;
    int by = bid & 15; bid >>= 4;
    int n = bid;
    int x0 = bx * 8, y0 = by * 8;

    for (int i = t; i < 8 * 144; i += 256) {
        int k = i / 144;
        int rem = i - k * 144;
        int r = rem / 12, c = rem - r * 12;
        int y = y0 - 2 + r, x = x0 - 2 + c;
        float v = 0.f;
        if ((unsigned)y < 128u && (unsigned)x < 128u)
            v = seg[((size_t)(n * 8 + k) * 128 + y) * 128 + x];
        sl[k][r][c] = v;
    }
    __syncthreads();   // stm ready

    float mn0 = stm[0], mn1 = stm[1], mn2 = stm[2];
    float rs0 = stm[3], rs1 = stm[4], rs2 = stm[5];

    for (int i = t; i < 432; i += 256) {
        int ch = i / 144; int pix = i - ch * 144;
        int r = pix / 12, c = pix - r * 12;
        int y = y0 - 2 + r, x = x0 - 2 + c;
        float v = 0.f;
        if ((unsigned)y < 128u && (unsigned)x < 128u) {
            float raw = img[(((size_t)(n * 3 + ch)) << 14) + y * 128 + x];
            float mn = ch == 0 ? mn0 : (ch == 1 ? mn1 : mn2);
            float rs = ch == 0 ? rs0 : (ch == 1 ? rs1 : rs2);
            v = (raw - mn) * rs;
        }
        il[r][c][ch] = v;
    }
    __syncthreads();

    const float minus_inv2s2 = -1.0f / (2.0f * 0.2f * 0.2f); // -12.5
    float c0 = il[ty + 2][tx + 2][0];
    float c1 = il[ty + 2][tx + 2][1];
    float c2 = il[ty + 2][tx + 2][2];

    float wgt[25];
    float w1 = 0.f;
#pragma unroll
    for (int di = 0; di < 5; ++di)
#pragma unroll
        for (int dj = 0; dj < 5; ++dj) {
            int y2 = y0 + ty + di - 2, x2 = x0 + tx + dj - 2;
            float bias = ((unsigned)y2 < 128u && (unsigned)x2 < 128u) ? 0.f : 1e30f;
            const float* np = &il[ty + di][tx + dj][0];
            float e0 = c0 - np[0], e1 = c1 - np[1], e2 = c2 - np[2];
            float d = bias + fmaf(e2, e2, fmaf(e1, e1, e0 * e0));
            float wv = __expf(d * minus_inv2s2);
            wgt[di * 5 + dj] = wv;
            w1 += wv;
        }

#pragma unroll
    for (int kk = 0; kk < 2; ++kk) {
        int k = w * 2 + kk;
        float s = 0.f;
#pragma unroll
        for (int di = 0; di < 5; ++di)
#pragma unroll
            for (int dj = 0; dj < 5; ++dj)
                s = fmaf(wgt[di * 5 + dj], sl[k][ty + di][tx + dj], s);
        float sc = sl[k][ty + 2][tx + 2];
        float numk = s * sc;
        float denk = w1 * sc;
#pragma unroll
        for (int sft = 32; sft > 0; sft >>= 1) {
            numk += __shfl_xor(numk, sft, 64);
            denk += __shfl_xor(denk, sft, 64);
        }
        if (lane == 0) {
            gstore(&part[(size_t)obid * 16 + k * 2], numk);
            gstore(&part[(size_t)obid * 16 + k * 2 + 1], denk);
        }
    }
}

// ---------------- merged modularity + ticket finalize -----------------------
// 1280 blocks; bid%5==0 -> mod64 (256), else mod128 (1024). Last block to
// finish reduces all partials and writes the loss.
__global__ __launch_bounds__(256) void modularity_all(
    const float* __restrict__ xt,   // FICH
    const float* __restrict__ seg,
    const float* __restrict__ st,   // fich rstd (from conv4_bn ticket)
    const float* __restrict__ img,
    const float* __restrict__ pimg,
    float* __restrict__ p64, float* __restrict__ p128,
    float* __restrict__ out, int* __restrict__ cnt)
{
    __shared__ float fl[4 * 2880];
    __shared__ float sl[8][12][14];
    __shared__ float stm[6];
    __shared__ int lastf;

    int bid = blockIdx.x;
    int tid = threadIdx.x;
    int g = bid / 5;
    int r5 = bid - g * 5;
    if (r5 == 0) {
        mod64_body(g, xt, seg, st, p64, fl, sl);
    } else {
        mod128_body(bid - g - 1, img, pimg, seg, p128,
                    (float(*)[12][4])fl, sl, stm);
    }

    // ---- ticket: last block reduces + finalizes ----
    __syncthreads();    // drains all waves' global stores before counting
    if (tid == 0) {
        int old = __hip_atomic_fetch_add(cnt, 1, __ATOMIC_ACQ_REL, __HIP_MEMORY_SCOPE_AGENT);
        lastf = (old == 1279);
    }
    __syncthreads();
    if (!lastf) return;

    int j = tid >> 2, s4 = tid & 3;   // 64 groups x 4 threads
    float num = 0.f, den = 0.f;
    if (j < 32) {
        int n = j >> 3, k = j & 7;
        for (int i = 0; i < 16; ++i) {
            int b = s4 * 16 + i;
            const float* p = p64 + ((size_t)(n * 64 + b)) * 16 + k * 2;
            num += gload(p); den += gload(p + 1);
        }
    } else {
        int jj = j - 32; int n = jj >> 3, k = jj & 7;
        for (int i = 0; i < 64; ++i) {
            int b = s4 * 64 + i;
            const float* p = p128 + ((size_t)(n * 256 + b)) * 16 + k * 2;
            num += gload(p); den += gload(p + 1);
        }
    }
    num += __shfl_xor(num, 1, 64); den += __shfl_xor(den, 1, 64);
    num += __shfl_xor(num, 2, 64); den += __shfl_xor(den, 2, 64);
    if (s4 == 0) { fl[j] = num; fl[64 + j] = den; }
    __syncthreads();
    if (tid < 64) {
        float v = fl[tid] / fl[64 + tid];
#pragma unroll
        for (int sh = 32; sh > 0; sh >>= 1) v += __shfl_xor(v, sh, 64);
        if (tid == 0) out[0] = v * (1.0f / 64.0f);
    }
}

extern "C" void kernel_launch(void* const* d_in, const int* in_sizes, int n_in,
                              void* d_out, int out_size, void* d_ws, size_t ws_size,
                              hipStream_t stream)
{
    const float* images = (const float*)d_in[0];
    const float* seg    = (const float*)d_in[1];
    const float* w1 = (const float*)d_in[2]; const float* b1 = (const float*)d_in[3];
    const float* w2 = (const float*)d_in[4]; const float* b2 = (const float*)d_in[5];
    const float* w3 = (const float*)d_in[6]; const float* b3 = (const float*)d_in[7];
    const float* w4 = (const float*)d_in[8]; const float* b4 = (const float*)d_in[9];
    float* out = (float*)d_out;
    char* ws = (char*)d_ws;
    short* PAD2 = (short*)(ws + OFF_PAD2);
    short* PAD3 = (short*)(ws + OFF_PAD3);
    short* PAD4 = (short*)(ws + OFF_PAD4);
    float* FICH = (float*)(ws + OFF_FICH);
    short* WP2  = (short*)(ws + OFF_WP2);
    short* WP3  = (short*)(ws + OFF_WP3);
    short* WP4  = (short*)(ws + OFF_WP4);
    float* ST   = (float*)(ws + OFF_ST);
    float* P64  = (float*)(ws + OFF_P64);
    float* P128 = (float*)(ws + OFF_P128);
    float* PBN  = (float*)(ws + OFF_PBN);
    float* PIMG = (float*)(ws + OFF_PIMG);
    int*   CNT  = (int*)(ws + OFF_CNT);
    int*   CNT2 = (int*)(ws + OFF_CNT2);

    // 1: halos + weight prepack + image BN partials + conv1 + ticket zero
    prologue<<<3410, 256, 0, stream>>>(ws, images, w1, b1, w2, w3, w4);
    // 2: conv1_2 + fused 2x2 maxpool (4 conv rows/block)
    conv2_pool<<<512, 256, 0, stream>>>(PAD2, WP2, b2, PAD3);
    // 3: conv2_1 (2 rows/block)
    conv3_2row<<<512, 256, 0, stream>>>(PAD3, WP3, b3, PAD4);
    // 4: conv2_2 + BN partials + ST finalize (ticket, once)
    conv4_bn<<<512, 256, 0, stream>>>(PAD4, WP4, b4, FICH, PBN, ST, CNT2);
    // 5: both modularity terms + loss (ticket)
    modularity_all<<<1280, 256, 0, stream>>>(FICH, seg, ST, images, PIMG,
                                             P64, P128, out, CNT);
}

// Round 4
// 162.606 us; speedup vs baseline: 1.2123x; 1.2123x over previous
//
#include <hip/hip_runtime.h>
#include <hip/hip_bf16.h>
#include <math.h>

typedef __attribute__((ext_vector_type(8))) short short8;
typedef __attribute__((ext_vector_type(4))) float floatx4;
typedef unsigned short ushortT;

__device__ inline short f2bf(float v) {
    __hip_bfloat16 h = __float2bfloat16(v);
    union { __hip_bfloat16 h; short s; } u; u.h = h; return u.s;
}

// ---------------- workspace layout (bytes), all disjoint ----------------
#define OFF_C2    0
#define OFF_PAD4  8388608
#define OFF_FICH  12849152
#define OFF_PAD2  21237760
#define OFF_PAD3  29890560
#define OFF_WP2   32120832
#define OFF_WP3   32194560
#define OFF_WP4   32342016
#define OFF_ST    33947648   // [0..127] rstdF
#define OFF_P64   33951744   // 256 x 16 floats mod64 partials
#define OFF_P128  33968128   // 1024 x 16 floats mod128 partials
#define OFF_PBN   34033664   // 512 x 64 floats conv4 bn partials (128KB)
#define OFF_PIMG  34295808   // 192 x 2 floats image bn partials

// ---------------- prologue: halos + weight prepack + image bnsum + conv1 ----
__global__ __launch_bounds__(256) void prologue(
    char* ws, const float* __restrict__ images,
    const float* __restrict__ w1, const float* __restrict__ b1,
    const float* __restrict__ w2, const float* __restrict__ w3,
    const float* __restrict__ w4)
{
    __shared__ float plds[3 * 720];
    __shared__ float rs[256], rs2[256];

    int b = blockIdx.x;
    int tid = threadIdx.x;

    if (b >= 1362) {
        // ---- conv1 body ----
        int bid = b - 1362;                   // 4n x 8ocg x 8ty x 8tx
        int txt = bid & 7; bid >>= 3;
        int tyt = bid & 7; bid >>= 3;
        int ocg = bid & 7; bid >>= 3;
        int n = bid;
        int x0 = txt * 16, y0 = tyt * 16;
        int tx = tid & 15, ty = tid >> 4;
        short* outp = (short*)(ws + OFF_PAD2);

        for (int i = tid; i < 972; i += 256) {
            int cc = i / 324; int rem = i - cc * 324;
            int r = rem / 18, c = rem - r * 18;
            int y = y0 - 1 + r, x = x0 - 1 + c;
            float v = 0.f;
            if ((unsigned)y < 128u && (unsigned)x < 128u)
                v = images[((size_t)(n * 3 + cc) * 128 + y) * 128 + x];
            plds[cc * 720 + r * 40 + c] = v;
        }
        __syncthreads();

        float acc[8];
#pragma unroll
        for (int oc = 0; oc < 8; ++oc) acc[oc] = 0.f;
        const float* w_g = w1 + (size_t)(ocg * 8) * 27;
#pragma unroll
        for (int cc = 0; cc < 3; ++cc) {
            const float* base = &plds[cc * 720 + ty * 40 + tx];
            float i00 = base[0],  i01 = base[1],  i02 = base[2];
            float i10 = base[40], i11 = base[41], i12 = base[42];
            float i20 = base[80], i21 = base[81], i22 = base[82];
            const float* wp = w_g + cc * 9;
#pragma unroll
            for (int oc = 0; oc < 8; ++oc) {
                const float* wq = wp + oc * 27;
                float a = acc[oc];
                a = fmaf(wq[0], i00, a); a = fmaf(wq[1], i01, a); a = fmaf(wq[2], i02, a);
                a = fmaf(wq[3], i10, a); a = fmaf(wq[4], i11, a); a = fmaf(wq[5], i12, a);
                a = fmaf(wq[6], i20, a); a = fmaf(wq[7], i21, a); a = fmaf(wq[8], i22, a);
                acc[oc] = a;
            }
        }
        int oy = y0 + ty, ox = x0 + tx;
        short* o = outp + ((size_t)(n * 130 + oy + 1) * 130 + ox + 1) * 64 + ocg * 8;
#pragma unroll
        for (int oc = 0; oc < 8; ++oc) {
            float v = fmaxf(acc[oc] + b1[ocg * 8 + oc], 0.f);
            o[oc] = f2bf(v);
        }
        return;
    }

    if (b < 162) {
        int t = b * 256 + tid;
        short* base; int Hp, Wp, C; int idx;
        if (t < 16512)      { base = (short*)(ws + OFF_PAD2); Hp = 130; Wp = 130; C = 64;  idx = t; }
        else if (t < 24832) { base = (short*)(ws + OFF_PAD3); Hp = 66;  Wp = 66;  C = 64;  idx = t - 16512; }
        else if (t < 41472) { base = (short*)(ws + OFF_PAD4); Hp = 66;  Wp = 66;  C = 128; idx = t - 24832; }
        else return;
        int c8 = idx % (C / 8); int rest = idx / (C / 8);
        int haloPx = 2 * Wp + 2 * (Hp - 2);
        int p = rest % haloPx; int n = rest / haloPx;
        int y, x;
        if (p < Wp)          { y = 0;      x = p; }
        else if (p < 2 * Wp) { y = Hp - 1; x = p - Wp; }
        else { int j = p - 2 * Wp; y = 1 + (j >> 1); x = (j & 1) ? (Wp - 1) : 0; }
        short8 z = {0, 0, 0, 0, 0, 0, 0, 0};
        *(short8*)&base[((size_t)((n * Hp + y) * Wp) + x) * C + c8 * 8] = z;
        return;
    }
    if (b < 1170) {
        int e = (b - 162) * 256 + tid;
        const float* w; short* wp; int CIN, NTALL;
        if (e < 36864)       { w = w2; wp = (short*)(ws + OFF_WP2); CIN = 64;  NTALL = 4; }
        else if (e < 110592) { e -= 36864;  w = w3; wp = (short*)(ws + OFF_WP3); CIN = 64;  NTALL = 8; }
        else if (e < 258048) { e -= 110592; w = w4; wp = (short*)(ws + OFF_WP4); CIN = 128; NTALL = 8; }
        else return;
        int j = e & 7; int L = (e >> 3) & 63; int rest = e >> 9;
        int nt = rest % NTALL; int rest2 = rest / NTALL;
        int KT = CIN / 32;
        int kt = rest2 % KT; int t = rest2 / KT;
        int oc = nt * 16 + (L & 15);
        int ci = kt * 32 + (L >> 4) * 8 + j;
        wp[e] = f2bf(w[((size_t)oc * CIN + ci) * 9 + t]);
        return;
    }
    {
        float* part = (float*)(ws + OFF_PIMG);
        int bb = b - 1170;           // c(3) x chunk(64)
        int c = bb >> 6, chunk = bb & 63;
        int base = chunk * 1024 + tid;
        float s = 0.f, s2 = 0.f;
#pragma unroll
        for (int k = 0; k < 4; ++k) {
            int i = base + k * 256;
            int n = i >> 14, hw = i & 16383;
            float v = images[(((size_t)(n * 3 + c)) << 14) + hw];
            s += v; s2 = fmaf(v, v, s2);
        }
        rs[tid] = s; rs2[tid] = s2;
        __syncthreads();
        for (int k = 128; k > 0; k >>= 1) {
            if (tid < k) { rs[tid] += rs[tid + k]; rs2[tid] += rs2[tid + k]; }
            __syncthreads();
        }
        if (tid == 0) { part[bb * 2] = rs[0]; part[bb * 2 + 1] = rs2[0]; }
    }
}

// ---------------- conv2 (64->64, 128x128) + fused 2x2 maxpool ---------------
// 4 conv rows (2 pooled rows) per block, oc split 2-way: 512 blocks.
__global__ __launch_bounds__(256) void conv2_pool(
    const short* __restrict__ inp,  // PAD2 (4,130,130,64) bf16
    const short* __restrict__ wp,   // WP2
    const float* __restrict__ bias,
    short* __restrict__ outp)       // PAD3 (4,66,66,64) bf16
{
    constexpr int CIN = 64;
    constexpr int Hp = 130, Wp = 130;

    int bid = blockIdx.x;           // 512 = n4 x yq32 x xt2 x o2
    int o2 = bid & 1; bid >>= 1;
    int xt = bid & 1; bid >>= 1;
    int yq = bid & 31; bid >>= 5;
    int n = bid;
    int y0 = yq * 4;
    int x0 = xt * 64;

    int tid = threadIdx.x;
    int wv = tid >> 6, lane = tid & 63;
    int lm = lane & 15, q = lane >> 4;
    int px0 = x0 + 16 * wv;
    int ntb = o2 * 2;               // 2 nt-tiles = 32 oc

    floatx4 acc[4][2];
#pragma unroll
    for (int d = 0; d < 4; ++d)
#pragma unroll
        for (int t = 0; t < 2; ++t) acc[d][t] = (floatx4){0.f, 0.f, 0.f, 0.f};

    const short* a_m = inp + lm * CIN + q * 8;
    const short* wbase = wp + ((size_t)ntb * 64 + lane) * 8;

    for (int kt = 0; kt < 2; ++kt) {
        int kofs = kt * 32;
#pragma unroll
        for (int s = 0; s < 3; ++s) {
            const short* acol = a_m + ((size_t)((n * Hp + y0) * Wp) + px0 + s) * CIN + kofs;
            short8 av[6];
#pragma unroll
            for (int j = 0; j < 6; ++j)
                av[j] = *(const short8*)(acol + (size_t)j * Wp * CIN);
#pragma unroll
            for (int r = 0; r < 3; ++r) {
                const short* bp = wbase + (size_t)(((r * 3 + s) * 2 + kt) * 4) * 512;
                short8 b0 = *(const short8*)bp;
                short8 b1 = *(const short8*)(bp + 512);
#pragma unroll
                for (int d = 0; d < 4; ++d) {
                    acc[d][0] = __builtin_amdgcn_mfma_f32_16x16x32_bf16(av[r + d], b0, acc[d][0], 0, 0, 0);
                    acc[d][1] = __builtin_amdgcn_mfma_f32_16x16x32_bf16(av[r + d], b1, acc[d][1], 0, 0, 0);
                }
            }
        }
    }

    int ox = (px0 + q * 4) >> 1;
#pragma unroll
    for (int t2 = 0; t2 < 2; ++t2) {
        int oc = (ntb + t2) * 16 + lm;
        float bs = bias[oc];
#pragma unroll
        for (int p = 0; p < 2; ++p) {
            float v00 = fmaxf(acc[2 * p][t2][0] + bs, 0.f);
            float v01 = fmaxf(acc[2 * p][t2][1] + bs, 0.f);
            float v02 = fmaxf(acc[2 * p][t2][2] + bs, 0.f);
            float v03 = fmaxf(acc[2 * p][t2][3] + bs, 0.f);
            float v10 = fmaxf(acc[2 * p + 1][t2][0] + bs, 0.f);
            float v11 = fmaxf(acc[2 * p + 1][t2][1] + bs, 0.f);
            float v12 = fmaxf(acc[2 * p + 1][t2][2] + bs, 0.f);
            float v13 = fmaxf(acc[2 * p + 1][t2][3] + bs, 0.f);
            float m0 = fmaxf(fmaxf(v00, v01), fmaxf(v10, v11));
            float m1 = fmaxf(fmaxf(v02, v03), fmaxf(v12, v13));
            int oy = yq * 2 + p;
            short* o = outp + ((size_t)(n * 66 + oy + 1) * 66 + ox + 1) * 64 + oc;
            o[0]  = f2bf(m0);
            o[64] = f2bf(m1);
        }
    }
}

// ---------------- mod128 body (plain stores) --------------------------------
__device__ __forceinline__ void mod128_body(
    int obid,
    const float* __restrict__ img, const float* __restrict__ pimg,
    const float* __restrict__ seg, float* __restrict__ part,
    float (*il)[12][4], float (*sl)[12][14], float* stm)
{
    int t = threadIdx.x;            // 256
    int w = t >> 6, lane = t & 63;
    int tx = lane & 7, ty = lane >> 3;

    if (t < 64) {
#pragma unroll
        for (int ch = 0; ch < 3; ++ch) {
            float s  = pimg[(ch * 64 + t) * 2];
            float s2 = pimg[(ch * 64 + t) * 2 + 1];
#pragma unroll
            for (int sh = 32; sh > 0; sh >>= 1) {
                s += __shfl_xor(s, sh, 64);
                s2 += __shfl_xor(s2, sh, 64);
            }
            if (t == 0) {
                float mean = s * (1.f / 65536.f);
                float var = s2 * (1.f / 65536.f) - mean * mean;
                stm[ch] = mean;
                stm[3 + ch] = 1.f / sqrtf(var + 1e-5f);
            }
        }
    }

    int bid = obid;                    // n(4) x by(16) x bx(16)
    int bx = bid & 15; bid >>= 4;
    int by = bid & 15; bid >>= 4;
    int n = bid;
    int x0 = bx * 8, y0 = by * 8;

    for (int i = t; i < 8 * 144; i += 256) {
        int k = i / 144;
        int rem = i - k * 144;
        int r = rem / 12, c = rem - r * 12;
        int y = y0 - 2 + r, x = x0 - 2 + c;
        float v = 0.f;
        if ((unsigned)y < 128u && (unsigned)x < 128u)
            v = seg[((size_t)(n * 8 + k) * 128 + y) * 128 + x];
        sl[k][r][c] = v;
    }
    __syncthreads();   // stm ready

    float mn0 = stm[0], mn1 = stm[1], mn2 = stm[2];
    float rs0 = stm[3], rs1 = stm[4], rs2 = stm[5];

    for (int i = t; i < 432; i += 256) {
        int ch = i / 144; int pix = i - ch * 144;
        int r = pix / 12, c = pix - r * 12;
        int y = y0 - 2 + r, x = x0 - 2 + c;
        float v = 0.f;
        if ((unsigned)y < 128u && (unsigned)x < 128u) {
            float raw = img[(((size_t)(n * 3 + ch)) << 14) + y * 128 + x];
            float mn = ch == 0 ? mn0 : (ch == 1 ? mn1 : mn2);
            float rs = ch == 0 ? rs0 : (ch == 1 ? rs1 : rs2);
            v = (raw - mn) * rs;
        }
        il[r][c][ch] = v;
    }
    __syncthreads();

    const float minus_inv2s2 = -1.0f / (2.0f * 0.2f * 0.2f); // -12.5
    float c0 = il[ty + 2][tx + 2][0];
    float c1 = il[ty + 2][tx + 2][1];
    float c2 = il[ty + 2][tx + 2][2];

    float wgt[25];
    float w1 = 0.f;
#pragma unroll
    for (int di = 0; di < 5; ++di)
#pragma unroll
        for (int dj = 0; dj < 5; ++dj) {
            int y2 = y0 + ty + di - 2, x2 = x0 + tx + dj - 2;
            float bias = ((unsigned)y2 < 128u && (unsigned)x2 < 128u) ? 0.f : 1e30f;
            const float* np = &il[ty + di][tx + dj][0];
            float e0 = c0 - np[0], e1 = c1 - np[1], e2 = c2 - np[2];
            float d = bias + fmaf(e2, e2, fmaf(e1, e1, e0 * e0));
            float wv = __expf(d * minus_inv2s2);
            wgt[di * 5 + dj] = wv;
            w1 += wv;
        }

#pragma unroll
    for (int kk = 0; kk < 2; ++kk) {
        int k = w * 2 + kk;
        float s = 0.f;
#pragma unroll
        for (int di = 0; di < 5; ++di)
#pragma unroll
            for (int dj = 0; dj < 5; ++dj)
                s = fmaf(wgt[di * 5 + dj], sl[k][ty + di][tx + dj], s);
        float sc = sl[k][ty + 2][tx + 2];
        float numk = s * sc;
        float denk = w1 * sc;
#pragma unroll
        for (int sft = 32; sft > 0; sft >>= 1) {
            numk += __shfl_xor(numk, sft, 64);
            denk += __shfl_xor(denk, sft, 64);
        }
        if (lane == 0) {
            part[(size_t)obid * 16 + k * 2] = numk;
            part[(size_t)obid * 16 + k * 2 + 1] = denk;
        }
    }
}

// ---------------- conv3 (64->128) MERGED with mod128 ------------------------
// 1536 blocks: bid<512 conv3 (2 rows/block, oc split 4); bid>=512 mod128.
// mod128 depends only on prologue outputs, so it backfills conv3's idle SIMDs.
__global__ __launch_bounds__(256) void conv3_mod128(
    const short* __restrict__ inp,  // PAD3 (4,66,66,64)
    const short* __restrict__ wp,   // WP3
    const float* __restrict__ bias,
    short* __restrict__ outp,       // PAD4 (4,66,66,128) interior
    const float* __restrict__ img,
    const float* __restrict__ pimg,
    const float* __restrict__ seg,
    float* __restrict__ p128)
{
    __shared__ float il[12][12][4];
    __shared__ float sl[8][12][14];
    __shared__ float stm[6];

    if (blockIdx.x >= 512) {
        mod128_body(blockIdx.x - 512, img, pimg, seg, p128, il, sl, stm);
        return;
    }

    constexpr int CIN = 64, COUT = 128, Hp = 66, Wp = 66, KT = 2, NTALL = 8;

    int bid = blockIdx.x;           // 512 = n4 x yq32 x bn4
    int bn = bid & 3; bid >>= 2;
    int yq = bid & 31; bid >>= 5;
    int n = bid;
    int y0 = yq * 2;

    int tid = threadIdx.x;
    int wv = tid >> 6, lane = tid & 63;
    int lm = lane & 15, q = lane >> 4;
    int px0 = 16 * wv;
    int ntb = bn * 2;

    floatx4 acc[2][2];
#pragma unroll
    for (int d = 0; d < 2; ++d)
#pragma unroll
        for (int t = 0; t < 2; ++t) acc[d][t] = (floatx4){0.f, 0.f, 0.f, 0.f};

    const short* a_m = inp + lm * CIN + q * 8;
    const short* wbase = wp + ((size_t)ntb * 64 + lane) * 8;

    for (int kt = 0; kt < KT; ++kt) {
        int kofs = kt * 32;
#pragma unroll
        for (int s = 0; s < 3; ++s) {
            const short* acol = a_m + ((size_t)((n * Hp + y0) * Wp) + px0 + s) * CIN + kofs;
            short8 av[4];
#pragma unroll
            for (int j = 0; j < 4; ++j)
                av[j] = *(const short8*)(acol + (size_t)j * Wp * CIN);
#pragma unroll
            for (int r = 0; r < 3; ++r) {
                const short* bp = wbase + (size_t)(((r * 3 + s) * KT + kt) * NTALL) * 512;
                short8 b0 = *(const short8*)bp;
                short8 b1 = *(const short8*)(bp + 512);
#pragma unroll
                for (int d = 0; d < 2; ++d) {
                    acc[d][0] = __builtin_amdgcn_mfma_f32_16x16x32_bf16(av[r + d], b0, acc[d][0], 0, 0, 0);
                    acc[d][1] = __builtin_amdgcn_mfma_f32_16x16x32_bf16(av[r + d], b1, acc[d][1], 0, 0, 0);
                }
            }
        }
    }

#pragma unroll
    for (int t2 = 0; t2 < 2; ++t2) {
        int oc = (ntb + t2) * 16 + lm;
        float bs = bias[oc];
#pragma unroll
        for (int d = 0; d < 2; ++d) {
#pragma unroll
            for (int i = 0; i < 4; ++i) {
                int px = px0 + q * 4 + i;
                float v = fmaxf(acc[d][t2][i] + bs, 0.f);
                outp[((size_t)(n * Hp + y0 + d + 1) * Wp + px + 1) * COUT + oc] = f2bf(v);
            }
        }
    }
}

// ---------------- conv4 (128->128, 64x64): 2 rows/block + BN partials -------
__global__ __launch_bounds__(256) void conv4_bn(
    const short* __restrict__ inp,  // PAD4 (4,66,66,128)
    const short* __restrict__ wp,   // WP4
    const float* __restrict__ bias,
    float* __restrict__ out,        // FICH (4,64,64,128) f32
    float* __restrict__ part)       // [512][64]: (sum,sumsq) x 32ch per block
{
    constexpr int CIN = 128, Hp = 66, Wp = 66, KT = 4, NTALL = 8;

    int bid = blockIdx.x;           // 512 = n4 x yq32 x bn4
    int bn = bid & 3; bid >>= 2;
    int yq = bid & 31; bid >>= 5;
    int n = bid;
    int y0 = yq * 2;

    int tid = threadIdx.x;
    int wv = tid >> 6, lane = tid & 63;
    int lm = lane & 15, q = lane >> 4;
    int px0 = 16 * wv;
    int ntb = bn * 2;

    floatx4 acc[2][2];
#pragma unroll
    for (int d = 0; d < 2; ++d)
#pragma unroll
        for (int t = 0; t < 2; ++t) acc[d][t] = (floatx4){0.f, 0.f, 0.f, 0.f};

    const short* a_m = inp + lm * CIN + q * 8;
    const short* wbase = wp + ((size_t)ntb * 64 + lane) * 8;

    for (int kt = 0; kt < KT; ++kt) {
        int kofs = kt * 32;
#pragma unroll
        for (int s = 0; s < 3; ++s) {
            const short* acol = a_m + ((size_t)((n * Hp + y0) * Wp) + px0 + s) * CIN + kofs;
            short8 av[4];
#pragma unroll
            for (int j = 0; j < 4; ++j)
                av[j] = *(const short8*)(acol + (size_t)j * Wp * CIN);
#pragma unroll
            for (int r = 0; r < 3; ++r) {
                const short* bp = wbase + (size_t)(((r * 3 + s) * KT + kt) * NTALL) * 512;
                short8 b0 = *(const short8*)bp;
                short8 b1 = *(const short8*)(bp + 512);
#pragma unroll
                for (int d = 0; d < 2; ++d) {
                    acc[d][0] = __builtin_amdgcn_mfma_f32_16x16x32_bf16(av[r + d], b0, acc[d][0], 0, 0, 0);
                    acc[d][1] = __builtin_amdgcn_mfma_f32_16x16x32_bf16(av[r + d], b1, acc[d][1], 0, 0, 0);
                }
            }
        }
    }

    __shared__ float ps[4][2][16], ps2[4][2][16];
#pragma unroll
    for (int t2 = 0; t2 < 2; ++t2) {
        int oc = (ntb + t2) * 16 + lm;
        float bs = bias[oc];
        float sv = 0.f, sv2 = 0.f;
#pragma unroll
        for (int d = 0; d < 2; ++d) {
#pragma unroll
            for (int i = 0; i < 4; ++i) {
                int px = px0 + q * 4 + i;
                float v = fmaxf(acc[d][t2][i] + bs, 0.f);
                out[((size_t)(n * 64 + y0 + d) * 64 + px) * 128 + oc] = v;
                sv += v; sv2 = fmaf(v, v, sv2);
            }
        }
        sv  += __shfl_xor(sv, 16, 64);  sv  += __shfl_xor(sv, 32, 64);
        sv2 += __shfl_xor(sv2, 16, 64); sv2 += __shfl_xor(sv2, 32, 64);
        if (q == 0) { ps[wv][t2][lm] = sv; ps2[wv][t2][lm] = sv2; }
    }
    __syncthreads();
    if (tid < 32) {
        int t_ = tid >> 4, lm_ = tid & 15;
        float a  = ps[0][t_][lm_] + ps[1][t_][lm_] + ps[2][t_][lm_] + ps[3][t_][lm_];
        float a2 = ps2[0][t_][lm_] + ps2[1][t_][lm_] + ps2[2][t_][lm_] + ps2[3][t_][lm_];
        part[(size_t)blockIdx.x * 64 + tid * 2]     = a;
        part[(size_t)blockIdx.x * 64 + tid * 2 + 1] = a2;
    }
}

// ---------------- finalize fich BN stats from conv4 partials ----------------
// PBN[b][2c+{0,1}] = (sum,sumsq) for channel (b&3)*32 + c
__global__ __launch_bounds__(256) void stats_fin(const float* __restrict__ part,
                                                 float* __restrict__ st)
{
    int ch = blockIdx.x;    // 128 channels
    int t = threadIdx.x;    // 256 (only 128 active)
    int bn = ch >> 5, lc = ch & 31;
    __shared__ float rs[128], rs2[128];
    if (t < 128) {
        const float* p = part + ((size_t)(t * 4 + bn)) * 64 + lc * 2;
        rs[t] = p[0]; rs2[t] = p[1];
    }
    __syncthreads();
    for (int k = 64; k > 0; k >>= 1) {
        if (t < k) { rs[t] += rs[t + k]; rs2[t] += rs2[t + k]; }
        __syncthreads();
    }
    if (t == 0) {
        float mean = rs[0] * (1.f / 16384.f);
        float var = rs2[0] * (1.f / 16384.f) - mean * mean;
        st[ch] = 1.f / sqrtf(var + 1e-5f);
    }
}

// ---------------- modularity on VGG features (solo, 256 blocks) -------------
__global__ __launch_bounds__(256) void modularity64(
    const float* __restrict__ xt,   // (4,64,64,128) RAW fich
    const float* __restrict__ seg,  // (4,8,128,128)
    const float* __restrict__ st,   // [0..127] rstd
    float* __restrict__ part)       // [256][16]
{
    __shared__ float fl[4 * 2880];
    __shared__ float sl[8][12][14];

    int tid = threadIdx.x;
    int w = tid >> 6, lane = tid & 63;
    int tx = lane & 7, ty = lane >> 3;
    int obid = blockIdx.x;
    int bid = obid;
    int bx = bid & 7; bid >>= 3;
    int by = bid & 7; bid >>= 3;
    int n = bid;
    int x0 = bx * 8, y0 = by * 8;

    for (int i = tid; i < 8 * 144; i += 256) {
        int k = i / 144;
        int rem = i - k * 144;
        int r = rem / 12, c = rem - r * 12;
        int y = y0 - 2 + r, x = x0 - 2 + c;
        float v = 0.f;
        if ((unsigned)y < 64u && (unsigned)x < 64u) {
            const float* p = seg + ((size_t)(n * 8 + k) * 128 + 2 * y) * 128 + 2 * x;
            float2 a = *(const float2*)p;
            float2 b = *(const float2*)(p + 128);
            v = 0.25f * ((a.x + a.y) + (b.x + b.y));
        }
        sl[k][r][c] = v;
    }

    float* slab = fl + w * 2880;

    float d2p[25];
#pragma unroll
    for (int di = 0; di < 5; ++di)
#pragma unroll
        for (int dj = 0; dj < 5; ++dj) {
            int y2 = y0 + ty + di - 2, x2 = x0 + tx + dj - 2;
            float bias = ((unsigned)y2 < 64u && (unsigned)x2 < 64u) ? 0.f : 1e30f;
            d2p[di * 5 + dj] = (w == 0) ? bias : 0.f;
        }

    for (int r8 = 0; r8 < 2; ++r8) {
        int ch0 = w * 32 + r8 * 16;
        for (int i = lane; i < 576; i += 64) {
            int pix = i >> 2, q = i & 3;
            int r = pix / 12, c = pix - r * 12;
            int y = y0 - 2 + r, x = x0 - 2 + c;
            float4 v = make_float4(0.f, 0.f, 0.f, 0.f);
            if ((unsigned)y < 64u && (unsigned)x < 64u) {
                v = *(const float4*)&xt[((size_t)((n * 64 + y) * 64 + x)) * 128 + ch0 + q * 4];
                float4 sv = *(const float4*)&st[ch0 + q * 4];
                v.x *= sv.x; v.y *= sv.y; v.z *= sv.z; v.w *= sv.w;
            }
            *(float4*)&slab[(r * 12 + c) * 20 + q * 4] = v;
        }

        const float* ctr = &slab[((ty + 2) * 12 + tx + 2) * 20];
        float4 c0 = *(const float4*)(ctr + 0);
        float4 c1 = *(const float4*)(ctr + 4);
        float4 c2 = *(const float4*)(ctr + 8);
        float4 c3 = *(const float4*)(ctr + 12);
#pragma unroll
        for (int di = 0; di < 5; ++di)
#pragma unroll
            for (int dj = 0; dj < 5; ++dj) {
                const float* np = &slab[((ty + di) * 12 + tx + dj) * 20];
                float4 v0 = *(const float4*)(np + 0);
                float4 v1 = *(const float4*)(np + 4);
                float4 v2 = *(const float4*)(np + 8);
                float4 v3 = *(const float4*)(np + 12);
                float d = d2p[di * 5 + dj];
                float e;
                e = c0.x - v0.x; d = fmaf(e, e, d);
                e = c0.y - v0.y; d = fmaf(e, e, d);
                e = c0.z - v0.z; d = fmaf(e, e, d);
                e = c0.w - v0.w; d = fmaf(e, e, d);
                e = c1.x - v1.x; d = fmaf(e, e, d);
                e = c1.y - v1.y; d = fmaf(e, e, d);
                e = c1.z - v1.z; d = fmaf(e, e, d);
                e = c1.w - v1.w; d = fmaf(e, e, d);
                e = c2.x - v2.x; d = fmaf(e, e, d);
                e = c2.y - v2.y; d = fmaf(e, e, d);
                e = c2.z - v2.z; d = fmaf(e, e, d);
                e = c2.w - v2.w; d = fmaf(e, e, d);
                e = c3.x - v3.x; d = fmaf(e, e, d);
                e = c3.y - v3.y; d = fmaf(e, e, d);
                e = c3.z - v3.z; d = fmaf(e, e, d);
                e = c3.w - v3.w; d = fmaf(e, e, d);
                d2p[di * 5 + dj] = d;
            }
    }

#pragma unroll
    for (int j = 0; j < 25; ++j) slab[lane * 25 + j] = d2p[j];
    __syncthreads();

    const float minus_inv2s2 = -1.0f / (2.0f * 0.02f * 0.02f); // -1250
    for (int i = tid; i < 1600; i += 256) {
        float d = fl[i] + fl[2880 + i] + fl[5760 + i] + fl[8640 + i];
        fl[i] = expf(d * minus_inv2s2);
    }
    __syncthreads();

    float wgt[25];
    float w1 = 0.f;
#pragma unroll
    for (int j = 0; j < 25; ++j) { wgt[j] = fl[lane * 25 + j]; w1 += wgt[j]; }
#pragma unroll
    for (int kk = 0; kk < 2; ++kk) {
        int k = w * 2 + kk;
        float s = 0.f;
#pragma unroll
        for (int di = 0; di < 5; ++di)
#pragma unroll
            for (int dj = 0; dj < 5; ++dj)
                s = fmaf(wgt[di * 5 + dj], sl[k][ty + di][tx + dj], s);
        float sc = sl[k][ty + 2][tx + 2];
        float numk = s * sc;
        float denk = w1 * sc;
#pragma unroll
        for (int sh = 32; sh > 0; sh >>= 1) {
            numk += __shfl_xor(numk, sh, 64);
            denk += __shfl_xor(denk, sh, 64);
        }
        if (lane == 0) {
            part[(size_t)obid * 16 + k * 2] = numk;
            part[(size_t)obid * 16 + k * 2 + 1] = denk;
        }
    }
}

// ---------------- reduce partials + finalize in one dispatch -----------------
__global__ __launch_bounds__(1024) void reduce_finalize(
    const float* __restrict__ p64, const float* __restrict__ p128,
    float* __restrict__ out)
{
    int t = threadIdx.x;          // 1024
    int j = t >> 4, s = t & 15;   // 64 groups x 16 threads
    float num = 0.f, den = 0.f;
    if (j < 32) {
        int n = j >> 3, k = j & 7;
#pragma unroll
        for (int i = 0; i < 4; ++i) {
            int b = s * 4 + i;
            const float* p = p64 + ((size_t)(n * 64 + b)) * 16 + k * 2;
            num += p[0]; den += p[1];
        }
    } else {
        int jj = j - 32; int n = jj >> 3, k = jj & 7;
#pragma unroll
        for (int i = 0; i < 16; ++i) {
            int b = s * 16 + i;
            const float* p = p128 + ((size_t)(n * 256 + b)) * 16 + k * 2;
            num += p[0]; den += p[1];
        }
    }
#pragma unroll
    for (int sh = 8; sh > 0; sh >>= 1) {
        num += __shfl_xor(num, sh, 16);
        den += __shfl_xor(den, sh, 16);
    }
    __shared__ float rn[64], rd[64];
    if (s == 0) { rn[j] = num; rd[j] = den; }
    __syncthreads();
    if (t < 64) {
        float v = rn[t] / rd[t];
#pragma unroll
        for (int sh = 32; sh > 0; sh >>= 1) v += __shfl_xor(v, sh, 64);
        if (t == 0) out[0] = v * (1.0f / 64.0f);
    }
}

extern "C" void kernel_launch(void* const* d_in, const int* in_sizes, int n_in,
                              void* d_out, int out_size, void* d_ws, size_t ws_size,
                              hipStream_t stream)
{
    const float* images = (const float*)d_in[0];
    const float* seg    = (const float*)d_in[1];
    const float* w1 = (const float*)d_in[2]; const float* b1 = (const float*)d_in[3];
    const float* w2 = (const float*)d_in[4]; const float* b2 = (const float*)d_in[5];
    const float* w3 = (const float*)d_in[6]; const float* b3 = (const float*)d_in[7];
    const float* w4 = (const float*)d_in[8]; const float* b4 = (const float*)d_in[9];
    float* out = (float*)d_out;
    char* ws = (char*)d_ws;
    short* PAD2 = (short*)(ws + OFF_PAD2);
    short* PAD3 = (short*)(ws + OFF_PAD3);
    short* PAD4 = (short*)(ws + OFF_PAD4);
    float* FICH = (float*)(ws + OFF_FICH);
    short* WP2  = (short*)(ws + OFF_WP2);
    short* WP3  = (short*)(ws + OFF_WP3);
    short* WP4  = (short*)(ws + OFF_WP4);
    float* ST   = (float*)(ws + OFF_ST);
    float* P64  = (float*)(ws + OFF_P64);
    float* P128 = (float*)(ws + OFF_P128);
    float* PBN  = (float*)(ws + OFF_PBN);
    float* PIMG = (float*)(ws + OFF_PIMG);

    // 1: halos + weight prepack + image BN partials + conv1
    prologue<<<3410, 256, 0, stream>>>(ws, images, w1, b1, w2, w3, w4);
    // 2: conv1_2 + fused 2x2 maxpool (4 conv rows/block)
    conv2_pool<<<512, 256, 0, stream>>>(PAD2, WP2, b2, PAD3);
    // 3: conv2_1 (2 rows/block) + mod128 backfill (indep of conv chain)
    conv3_mod128<<<1536, 256, 0, stream>>>(PAD3, WP3, b3, PAD4,
                                           images, PIMG, seg, P128);
    // 4: conv2_2 + BN partials (2 rows/block)
    conv4_bn<<<512, 256, 0, stream>>>(PAD4, WP4, b4, FICH, PBN);
    // 5: finalize fich BN rstd
    stats_fin<<<128, 256, 0, stream>>>(PBN, ST);
    // 6: modularity on VGG features (256 blocks, 1/CU)
    modularity64<<<256, 256, 0, stream>>>(FICH, seg, ST, P64);
    // 7: final reduce
    reduce_finalize<<<1, 1024, 0, stream>>>(P64, P128, out);
}